// Round 1
// baseline (215.774 us; speedup 1.0000x reference)
//
#include <hip/hip_runtime.h>

#define IN_F 4096
#define OUT_F 4096
#define NTOK 8192   // B*S = 4*2048
#define KDIM 4096

using i32x4 = __attribute__((ext_vector_type(4))) int;
using f32x4 = __attribute__((ext_vector_type(4))) float;

__device__ __forceinline__ void gload_lds16(const void* g, void* l) {
  __builtin_amdgcn_global_load_lds(
      (const __attribute__((address_space(1))) void*)g,
      (__attribute__((address_space(3))) void*)l, 16, 0, 0);
}

// ---------------- Pass 1: RMSNorm + per-token int8 absmax quant ------------
// One block (256 threads) per token. 4096 floats = 4 float4 per thread.
__global__ __launch_bounds__(256) void rmsq_kernel(
    const float* __restrict__ x, const float* __restrict__ rmsw,
    signed char* __restrict__ q, float* __restrict__ dscale) {
  const int tok = blockIdx.x;
  const int tid = threadIdx.x;
  const f32x4* xr = (const f32x4*)(x + (size_t)tok * IN_F);
  const f32x4* wr = (const f32x4*)rmsw;

  f32x4 v[4];
  float ss = 0.f;
#pragma unroll
  for (int c = 0; c < 4; ++c) {
    v[c] = xr[c * 256 + tid];
    ss += v[c].x * v[c].x + v[c].y * v[c].y + v[c].z * v[c].z + v[c].w * v[c].w;
  }

  __shared__ float red[4];
  // block-reduce sum of squares
#pragma unroll
  for (int off = 32; off > 0; off >>= 1) ss += __shfl_down(ss, off, 64);
  const int wid = tid >> 6;
  if ((tid & 63) == 0) red[wid] = ss;
  __syncthreads();
  const float tot = red[0] + red[1] + red[2] + red[3];
  const float rinv = rsqrtf(tot * (1.0f / IN_F) + 1e-6f);

  f32x4 h[4];
  float amax = 0.f;
#pragma unroll
  for (int c = 0; c < 4; ++c) {
    f32x4 w = wr[c * 256 + tid];
    h[c].x = v[c].x * rinv * w.x;
    h[c].y = v[c].y * rinv * w.y;
    h[c].z = v[c].z * rinv * w.z;
    h[c].w = v[c].w * rinv * w.w;
    amax = fmaxf(amax, fabsf(h[c].x));
    amax = fmaxf(amax, fabsf(h[c].y));
    amax = fmaxf(amax, fabsf(h[c].z));
    amax = fmaxf(amax, fabsf(h[c].w));
  }

  __syncthreads();  // protect red[] reuse
#pragma unroll
  for (int off = 32; off > 0; off >>= 1)
    amax = fmaxf(amax, __shfl_down(amax, off, 64));
  if ((tid & 63) == 0) red[wid] = amax;
  __syncthreads();
  amax = fmaxf(fmaxf(red[0], red[1]), fmaxf(red[2], red[3]));
  amax = fmaxf(amax, 1e-5f);  // clip(absmax, Q_EPS)
  const float qs = 127.0f / amax;
  if (tid == 0) dscale[tok] = amax * (1.0f / 127.0f);

  uint* qo = (uint*)(q + (size_t)tok * IN_F);
#pragma unroll
  for (int c = 0; c < 4; ++c) {
    float r0 = fminf(fmaxf(rintf(h[c].x * qs), -128.f), 127.f);
    float r1 = fminf(fmaxf(rintf(h[c].y * qs), -128.f), 127.f);
    float r2 = fminf(fmaxf(rintf(h[c].z * qs), -128.f), 127.f);
    float r3 = fminf(fmaxf(rintf(h[c].w * qs), -128.f), 127.f);
    uint p = ((uint)((int)r0 & 255)) | ((uint)((int)r1 & 255) << 8) |
             ((uint)((int)r2 & 255) << 16) | ((uint)((int)r3 & 255) << 24);
    qo[c * 256 + tid] = p;
  }
}

// ---------------- Pass 2: W float32 {-1,0,1} -> int8 ----------------------
__global__ __launch_bounds__(256) void wconv_kernel(
    const float* __restrict__ W, signed char* __restrict__ Wq) {
  const int idx = blockIdx.x * 256 + threadIdx.x;  // float4 index
  f32x4 w = ((const f32x4*)W)[idx];
  uint p = ((uint)((int)w.x & 255)) | ((uint)((int)w.y & 255) << 8) |
           ((uint)((int)w.z & 255) << 16) | ((uint)((int)w.w & 255) << 24);
  ((uint*)Wq)[idx] = p;
}

// ---------------- Pass 3: int8 GEMM + fused dequant epilogue ---------------
// C[m][n] = (acc[m][n] * dscale[m] + bias[n]) * wscale
// A = q [8192][4096] i8, Bw = Wq [4096][4096] i8 (N-major == B^T layout)
#define BM 128
#define BN 128
#define BK 64

__global__ __launch_bounds__(256) void gemm_kernel(
    const signed char* __restrict__ A, const signed char* __restrict__ Bw,
    const float* __restrict__ dscale, const float* __restrict__ bias,
    const float* __restrict__ wscale_p, float* __restrict__ out) {
  __shared__ signed char As[BM * BK];  // 8 KB
  __shared__ signed char Bs[BN * BK];  // 8 KB

  const int tid = threadIdx.x;
  const int lane = tid & 63;
  const int wid = tid >> 6;
  const int wr = wid >> 1;  // wave row (0..1), 64 output rows each
  const int wc = wid & 1;   // wave col (0..1), 64 output cols each
  const int m0 = blockIdx.x * BM;
  const int n0 = blockIdx.y * BN;

  i32x4 acc[4][4];
#pragma unroll
  for (int i = 0; i < 4; ++i)
#pragma unroll
    for (int j = 0; j < 4; ++j) acc[i][j] = (i32x4){0, 0, 0, 0};

  // staging: flat = tid + it*256; row = flat>>2 (64B rows), col = (flat&3)*16
  const int srow = tid >> 2;
  const int scol = (tid & 3) * 16;
  const signed char* Ag = A + (size_t)(m0 + srow) * KDIM + scol;
  const signed char* Bg = Bw + (size_t)(n0 + srow) * KDIM + scol;

  const int kgrp = (lane >> 4) * 16;  // K-chunk byte offset for this lane
  const int fr = lane & 15;           // fragment row/col

  for (int k0 = 0; k0 < KDIM; k0 += BK) {
    gload_lds16(Ag + k0, &As[tid * 16]);
    gload_lds16(Ag + k0 + (size_t)64 * KDIM, &As[tid * 16 + 4096]);
    gload_lds16(Bg + k0, &Bs[tid * 16]);
    gload_lds16(Bg + k0 + (size_t)64 * KDIM, &Bs[tid * 16 + 4096]);
    __syncthreads();  // compiler drains vmcnt before barrier

    i32x4 af[4], bf[4];
#pragma unroll
    for (int mi = 0; mi < 4; ++mi)
      af[mi] = *(const i32x4*)&As[(wr * 64 + mi * 16 + fr) * BK + kgrp];
#pragma unroll
    for (int ni = 0; ni < 4; ++ni)
      bf[ni] = *(const i32x4*)&Bs[(wc * 64 + ni * 16 + fr) * BK + kgrp];

#pragma unroll
    for (int mi = 0; mi < 4; ++mi)
#pragma unroll
      for (int ni = 0; ni < 4; ++ni)
        acc[mi][ni] = __builtin_amdgcn_mfma_i32_16x16x64_i8(af[mi], bf[ni],
                                                            acc[mi][ni], 0, 0, 0);
    __syncthreads();
  }

  // epilogue: D layout (16x16): col = lane&15, row = (lane>>4)*4 + reg
  const float wsc = wscale_p[0];
  const int rbase = (lane >> 4) * 4;
#pragma unroll
  for (int mi = 0; mi < 4; ++mi) {
#pragma unroll
    for (int r = 0; r < 4; ++r) {
      const int m = m0 + wr * 64 + mi * 16 + rbase + r;
      const float ds = dscale[m];
      float* orow = out + (size_t)m * OUT_F + n0 + wc * 64;
#pragma unroll
      for (int ni = 0; ni < 4; ++ni) {
        const int n = ni * 16 + fr;
        orow[n] = ((float)acc[mi][ni][r] * ds + bias[n0 + wc * 64 + n]) * wsc;
      }
    }
  }
}

extern "C" void kernel_launch(void* const* d_in, const int* in_sizes, int n_in,
                              void* d_out, int out_size, void* d_ws, size_t ws_size,
                              hipStream_t stream) {
  const float* x = (const float*)d_in[0];
  const float* W = (const float*)d_in[1];
  const float* rmsw = (const float*)d_in[2];
  const float* bias = (const float*)d_in[3];
  const float* wscale = (const float*)d_in[4];
  float* out = (float*)d_out;

  signed char* q = (signed char*)d_ws;                     // 33,554,432 B
  signed char* Wq = q + (size_t)NTOK * IN_F;               // 16,777,216 B
  float* dscale = (float*)(Wq + (size_t)OUT_F * IN_F);     // 32,768 B

  rmsq_kernel<<<NTOK, 256, 0, stream>>>(x, rmsw, q, dscale);
  wconv_kernel<<<(OUT_F * IN_F / 4) / 256, 256, 0, stream>>>(W, Wq);
  gemm_kernel<<<dim3(NTOK / BM, OUT_F / BN), 256, 0, stream>>>(q, Wq, dscale,
                                                               bias, wscale, out);
}

// Round 2
// 195.520 us; speedup vs baseline: 1.1036x; 1.1036x over previous
//
#include <hip/hip_runtime.h>

#define IN_F 4096
#define OUT_F 4096
#define NTOK 8192   // B*S = 4*2048
#define KDIM 4096

using i32x4 = __attribute__((ext_vector_type(4))) int;
using f32x4 = __attribute__((ext_vector_type(4))) float;

__device__ __forceinline__ void gload_lds16(const void* g, void* l) {
  __builtin_amdgcn_global_load_lds(
      (const __attribute__((address_space(1))) void*)g,
      (__attribute__((address_space(3))) void*)l, 16, 0, 0);
}

#define WAITV(n) asm volatile("s_waitcnt vmcnt(" #n ")" ::: "memory")
#define BAR() do { asm volatile("" ::: "memory"); __builtin_amdgcn_s_barrier(); \
                   asm volatile("" ::: "memory"); } while (0)

// ---------------- Pass 1: RMSNorm + per-token int8 absmax quant ------------
__global__ __launch_bounds__(256) void rmsq_kernel(
    const float* __restrict__ x, const float* __restrict__ rmsw,
    signed char* __restrict__ q, float* __restrict__ dscale) {
  const int tok = blockIdx.x;
  const int tid = threadIdx.x;
  const f32x4* xr = (const f32x4*)(x + (size_t)tok * IN_F);
  const f32x4* wr = (const f32x4*)rmsw;

  f32x4 v[4];
  float ss = 0.f;
#pragma unroll
  for (int c = 0; c < 4; ++c) {
    v[c] = xr[c * 256 + tid];
    ss += v[c].x * v[c].x + v[c].y * v[c].y + v[c].z * v[c].z + v[c].w * v[c].w;
  }

  __shared__ float red[4];
#pragma unroll
  for (int off = 32; off > 0; off >>= 1) ss += __shfl_down(ss, off, 64);
  const int wid = tid >> 6;
  if ((tid & 63) == 0) red[wid] = ss;
  __syncthreads();
  const float tot = red[0] + red[1] + red[2] + red[3];
  const float rinv = rsqrtf(tot * (1.0f / IN_F) + 1e-6f);

  f32x4 h[4];
  float amax = 0.f;
#pragma unroll
  for (int c = 0; c < 4; ++c) {
    f32x4 w = wr[c * 256 + tid];
    h[c].x = v[c].x * rinv * w.x;
    h[c].y = v[c].y * rinv * w.y;
    h[c].z = v[c].z * rinv * w.z;
    h[c].w = v[c].w * rinv * w.w;
    amax = fmaxf(amax, fabsf(h[c].x));
    amax = fmaxf(amax, fabsf(h[c].y));
    amax = fmaxf(amax, fabsf(h[c].z));
    amax = fmaxf(amax, fabsf(h[c].w));
  }

  __syncthreads();
#pragma unroll
  for (int off = 32; off > 0; off >>= 1)
    amax = fmaxf(amax, __shfl_down(amax, off, 64));
  if ((tid & 63) == 0) red[wid] = amax;
  __syncthreads();
  amax = fmaxf(fmaxf(red[0], red[1]), fmaxf(red[2], red[3]));
  amax = fmaxf(amax, 1e-5f);
  const float qs = 127.0f / amax;
  if (tid == 0) dscale[tok] = amax * (1.0f / 127.0f);

  uint* qo = (uint*)(q + (size_t)tok * IN_F);
#pragma unroll
  for (int c = 0; c < 4; ++c) {
    float r0 = fminf(fmaxf(rintf(h[c].x * qs), -128.f), 127.f);
    float r1 = fminf(fmaxf(rintf(h[c].y * qs), -128.f), 127.f);
    float r2 = fminf(fmaxf(rintf(h[c].z * qs), -128.f), 127.f);
    float r3 = fminf(fmaxf(rintf(h[c].w * qs), -128.f), 127.f);
    uint p = ((uint)((int)r0 & 255)) | ((uint)((int)r1 & 255) << 8) |
             ((uint)((int)r2 & 255) << 16) | ((uint)((int)r3 & 255) << 24);
    qo[c * 256 + tid] = p;
  }
}

// ---------------- Pass 2: W float32 {-1,0,1} -> int8 ----------------------
__global__ __launch_bounds__(256) void wconv_kernel(
    const float* __restrict__ W, signed char* __restrict__ Wq) {
  const int idx = blockIdx.x * 256 + threadIdx.x;
  f32x4 w = ((const f32x4*)W)[idx];
  uint p = ((uint)((int)w.x & 255)) | ((uint)((int)w.y & 255) << 8) |
           ((uint)((int)w.z & 255) << 16) | ((uint)((int)w.w & 255) << 24);
  ((uint*)Wq)[idx] = p;
}

// ---------------- Pass 3: deep-pipelined int8 GEMM -------------------------
// 256x256 tile, BK=64, 8 waves (2Mx4N), 3 LDS buffers, prefetch depth 2,
// counted vmcnt (never 0 in loop), slot-XOR LDS swizzle (involution, rule 21).
#define BM 256
#define BN 256
#define BK 64
#define NT (KDIM / BK)   // 64 K-tiles
#define ABYTES (BM * BK)          // 16384
#define BUFBYTES (2 * ABYTES)     // 32768 (A + B)

__global__ __launch_bounds__(512, 2) void gemm_kernel(
    const signed char* __restrict__ A, const signed char* __restrict__ Bw,
    const float* __restrict__ dscale, const float* __restrict__ bias,
    const float* __restrict__ wscale_p, float* __restrict__ out) {
  __shared__ __align__(16) signed char lds[3 * BUFBYTES];  // 96 KB

  const int tid = threadIdx.x;
  const int lane = tid & 63;
  const int wid = tid >> 6;
  const int wr = wid >> 2;  // 0..1 : 128 output rows
  const int wc = wid & 3;   // 0..3 : 64 output cols

  // XCD-aware bijective swizzle (512 blocks, 512%8==0)
  const int bid = blockIdx.x;
  const int swz = (bid & 7) * 64 + (bid >> 3);
  const int m0 = (swz & 31) * BM;   // 32 m-blocks
  const int n0 = (swz >> 5) * BN;   // 16 n-blocks

  // ---- staging constants (pre-swizzled global source, linear LDS dest) ----
  // chunk c: row r = c>>2, stored slot s' = c&3, logical slot s = s'^((r>>1)&3)
  const int cA0 = tid, cA1 = tid + 512;
  const int rA0 = cA0 >> 2, rA1 = cA1 >> 2;
  const int sA0 = (cA0 & 3) ^ ((rA0 >> 1) & 3);
  const int sA1 = (cA1 & 3) ^ ((rA1 >> 1) & 3);
  const signed char* agp0 = A + (size_t)(m0 + rA0) * KDIM + sA0 * 16;
  const signed char* agp1 = A + (size_t)(m0 + rA1) * KDIM + sA1 * 16;
  const signed char* bgp0 = Bw + (size_t)(n0 + rA0) * KDIM + sA0 * 16;
  const signed char* bgp1 = Bw + (size_t)(n0 + rA1) * KDIM + sA1 * 16;

#define STAGE(kt, bufb)                                                    \
  do {                                                                     \
    const int k0_ = (kt) * BK;                                             \
    signed char* lb_ = &lds[(bufb)];                                       \
    gload_lds16(agp0 + k0_, lb_ + cA0 * 16);                               \
    gload_lds16(agp1 + k0_, lb_ + cA1 * 16);                               \
    gload_lds16(bgp0 + k0_, lb_ + ABYTES + cA0 * 16);                      \
    gload_lds16(bgp1 + k0_, lb_ + ABYTES + cA1 * 16);                      \
  } while (0)

  // ---- fragment read offsets (swizzled, loop-invariant) ----
  const int fr = lane & 15;
  const int ks = lane >> 4;  // 16B k-slot
  int offA[8], offB[4];
#pragma unroll
  for (int mi = 0; mi < 8; ++mi) {
    const int row = wr * 128 + mi * 16 + fr;
    offA[mi] = row * BK + ((ks ^ ((row >> 1) & 3)) * 16);
  }
#pragma unroll
  for (int ni = 0; ni < 4; ++ni) {
    const int row = wc * 64 + ni * 16 + fr;
    offB[ni] = ABYTES + row * BK + ((ks ^ ((row >> 1) & 3)) * 16);
  }

  i32x4 acc[8][4];
#pragma unroll
  for (int i = 0; i < 8; ++i)
#pragma unroll
    for (int j = 0; j < 4; ++j) acc[i][j] = (i32x4){0, 0, 0, 0};

  // ---- prologue: fill the 3-deep pipeline ----
  STAGE(0, 0);
  STAGE(1, BUFBYTES);
  STAGE(2, 2 * BUFBYTES);

  int bufb = 0;
  for (int t = 0; t < NT; ++t) {
    // tile t landed when <= 8 newer loads outstanding (tiles t+1, t+2)
    if (t < NT - 2)       WAITV(8);
    else if (t == NT - 2) WAITV(4);
    else                  WAITV(0);
    BAR();  // all waves' tile-t loads complete

    const signed char* bp = &lds[bufb];
    i32x4 af[8], bf[4];
#pragma unroll
    for (int mi = 0; mi < 8; ++mi) af[mi] = *(const i32x4*)(bp + offA[mi]);
#pragma unroll
    for (int ni = 0; ni < 4; ++ni) bf[ni] = *(const i32x4*)(bp + offB[ni]);

    __builtin_amdgcn_s_setprio(1);
#pragma unroll
    for (int mi = 0; mi < 8; ++mi)
#pragma unroll
      for (int ni = 0; ni < 4; ++ni)
        acc[mi][ni] = __builtin_amdgcn_mfma_i32_16x16x64_i8(af[mi], bf[ni],
                                                            acc[mi][ni], 0, 0, 0);
    __builtin_amdgcn_s_setprio(0);
    BAR();  // all waves done reading buf -> safe to overwrite

    if (t + 3 < NT) STAGE(t + 3, bufb);
    bufb += BUFBYTES;
    if (bufb == 3 * BUFBYTES) bufb = 0;
  }

  // ---- epilogue: dequant + bias + weight_scale ----
  const float wsc = wscale_p[0];
  const int rbase = (lane >> 4) * 4;
  float bv[4];
#pragma unroll
  for (int ni = 0; ni < 4; ++ni) bv[ni] = bias[n0 + wc * 64 + ni * 16 + fr];
#pragma unroll
  for (int mi = 0; mi < 8; ++mi) {
#pragma unroll
    for (int r = 0; r < 4; ++r) {
      const int m = m0 + wr * 128 + mi * 16 + rbase + r;
      const float ds = dscale[m];
      float* orow = out + (size_t)m * OUT_F + n0 + wc * 64;
#pragma unroll
      for (int ni = 0; ni < 4; ++ni) {
        orow[ni * 16 + fr] = ((float)acc[mi][ni][r] * ds + bv[ni]) * wsc;
      }
    }
  }
#undef STAGE
}

extern "C" void kernel_launch(void* const* d_in, const int* in_sizes, int n_in,
                              void* d_out, int out_size, void* d_ws, size_t ws_size,
                              hipStream_t stream) {
  const float* x = (const float*)d_in[0];
  const float* W = (const float*)d_in[1];
  const float* rmsw = (const float*)d_in[2];
  const float* bias = (const float*)d_in[3];
  const float* wscale = (const float*)d_in[4];
  float* out = (float*)d_out;

  signed char* q = (signed char*)d_ws;                     // 32 MB
  signed char* Wq = q + (size_t)NTOK * IN_F;               // 16 MB
  float* dscale = (float*)(Wq + (size_t)OUT_F * IN_F);     // 32 KB

  rmsq_kernel<<<NTOK, 256, 0, stream>>>(x, rmsw, q, dscale);
  wconv_kernel<<<(OUT_F * IN_F / 4) / 256, 256, 0, stream>>>(W, Wq);
  gemm_kernel<<<(NTOK / BM) * (OUT_F / BN), 512, 0, stream>>>(q, Wq, dscale,
                                                              bias, wscale, out);
}